// Round 4
// baseline (299.940 us; speedup 1.0000x reference)
//
#include <hip/hip_runtime.h>
#include <stdint.h>

#define BB 32
#define L1 2048
#define L2 512
#define DD 256
#define NEGV -1e30f

typedef __attribute__((ext_vector_type(4))) float f32x4;
typedef __attribute__((ext_vector_type(8))) short bf16x8;
typedef __attribute__((ext_vector_type(4))) unsigned short u16x4;

__device__ __forceinline__ unsigned short f2bf(float f) {
    unsigned int u = __float_as_uint(f);
    u += 0x7FFFu + ((u >> 16) & 1u);
    return (unsigned short)(u >> 16);
}

// ---------------- prep_y: y -> bf16 row-major, sy = y @ w_y ----------------
__global__ void prep_y(const float* __restrict__ y, const float* __restrict__ w_y,
                       unsigned short* __restrict__ ybf, float* __restrict__ sy) {
    int row = blockIdx.x * 4 + (threadIdx.x >> 6);   // 0 .. BB*L2-1
    int lane = threadIdx.x & 63;
    const float* yr = y + (size_t)row * DD + lane * 4;
    f32x4 v = *(const f32x4*)yr;
    f32x4 w = *(const f32x4*)(w_y + lane * 4);
    u16x4 o;
    o[0] = f2bf(v[0]); o[1] = f2bf(v[1]); o[2] = f2bf(v[2]); o[3] = f2bf(v[3]);
    *(u16x4*)(ybf + (size_t)row * DD + lane * 4) = o;
    float s = v[0]*w[0] + v[1]*w[1] + v[2]*w[2] + v[3]*w[3];
    #pragma unroll
    for (int off = 32; off; off >>= 1) s += __shfl_down(s, off, 64);
    if (lane == 0) sy[row] = s;
}

// ---------------- transpose_y: y -> bf16 [b][d][j] ----------------
__global__ void transpose_y(const float* __restrict__ y, unsigned short* __restrict__ yt) {
    __shared__ float tile[64][65];
    int b = blockIdx.y;
    int jt = blockIdx.x & 7, dt = blockIdx.x >> 3;
    int j0 = jt * 64, d0 = dt * 64;
    const float* base = y + ((size_t)b * L2) * DD;
    #pragma unroll
    for (int k = 0; k < 16; ++k) {
        int idx = k * 256 + threadIdx.x;
        int jj = idx >> 6, dd = idx & 63;
        tile[jj][dd] = base[(size_t)(j0 + jj) * DD + d0 + dd];
    }
    __syncthreads();
    unsigned short* ob = yt + ((size_t)b * DD) * L2;
    #pragma unroll
    for (int k = 0; k < 16; ++k) {
        int idx = k * 256 + threadIdx.x;
        int dd = idx >> 6, jj = idx & 63;
        ob[(size_t)(d0 + dd) * L2 + j0 + jj] = f2bf(tile[jj][dd]);
    }
}

// ---------------- main fused attention kernel ----------------
// block = 256 threads (4 waves); wave w owns rows i0 = blockIdx.x*64 + w*16 .. +15
__launch_bounds__(256, 2)
__global__ void attn_main(const float* __restrict__ x,
                          const unsigned short* __restrict__ ybf,
                          const unsigned short* __restrict__ yt,
                          const float* __restrict__ sy,
                          const float* __restrict__ w_x,
                          const float* __restrict__ w_dot,
                          const float* __restrict__ bias,
                          const int* __restrict__ x_mask,
                          const int* __restrict__ y_mask,
                          float* __restrict__ rowmax,
                          float* __restrict__ out0,
                          float* __restrict__ out2) {
    __shared__ unsigned short alpha_lds[4][16][520];   // pad 512->520 kills b128 bank conflicts
    const int tid = threadIdx.x;
    const int w = tid >> 6;
    const int lane = tid & 63;
    const int g = lane >> 4, c = lane & 15;
    const int b = blockIdx.y;
    const int i0 = blockIdx.x * 64 + w * 16;

    // ---- build xw bf16 A-fragments in registers + sx via shuffles ----
    // A-frag layout (16x16x32): lane holds A[m=c][k = kb*32 + 8*g + e]
    bf16x8 afr[8];
    float sxpart = 0.f;
    const float* xrow = x + ((size_t)(b * L1 + i0 + c)) * DD;
    #pragma unroll
    for (int kb = 0; kb < 8; ++kb) {
        int koff = kb * 32 + g * 8;
        f32x4 lo = *(const f32x4*)(xrow + koff);
        f32x4 hi = *(const f32x4*)(xrow + koff + 4);
        f32x4 wdlo = *(const f32x4*)(w_dot + koff);
        f32x4 wdhi = *(const f32x4*)(w_dot + koff + 4);
        f32x4 wxlo = *(const f32x4*)(w_x + koff);
        f32x4 wxhi = *(const f32x4*)(w_x + koff + 4);
        bf16x8 a;
        #pragma unroll
        for (int e = 0; e < 4; ++e) {
            a[e]     = (short)f2bf(lo[e] * wdlo[e]);
            a[e + 4] = (short)f2bf(hi[e] * wdhi[e]);
            sxpart += lo[e] * wxlo[e] + hi[e] * wxhi[e];
        }
        afr[kb] = a;
    }
    // each lane holds a partial of sx[row c] over its g-slice; sum the 4 g-groups
    sxpart += __shfl_xor(sxpart, 16, 64);
    sxpart += __shfl_xor(sxpart, 32, 64);
    float bias0 = bias[0];
    float sxb[4];
    int xm[4];
    #pragma unroll
    for (int r = 0; r < 4; ++r) {
        sxb[r] = __shfl(sxpart, 4 * g + r, 64) + bias0;  // lane (4g+r) has sx of row 4g+r
        xm[r] = x_mask[b * L1 + i0 + 4 * g + r];
    }

    // ---- scores: S[16 rows][512] via MFMA, B-frags straight from row-major y_bf16 ----
    f32x4 S[32];
    const unsigned short* ybase = ybf + ((size_t)b * L2) * DD;
    #pragma unroll
    for (int jf = 0; jf < 32; ++jf) {
        f32x4 acc = {0.f, 0.f, 0.f, 0.f};
        const unsigned short* yb = ybase + (size_t)(jf * 16 + c) * DD + g * 8;
        #pragma unroll
        for (int kb = 0; kb < 8; ++kb) {
            bf16x8 bfr = *(const bf16x8*)(yb + kb * 32);
            acc = __builtin_amdgcn_mfma_f32_16x16x32_bf16(afr[kb], bfr, acc, 0, 0, 0);
        }
        float syv = sy[b * L2 + jf * 16 + c];
        int ym = y_mask[b * L2 + jf * 16 + c];
        #pragma unroll
        for (int r = 0; r < 4; ++r) {
            float v = acc[r] + sxb[r] + syv;
            if (ym) v = NEGV;
            if (xm[r]) v = NEGV;
            S[jf][r] = v;
        }
    }

    // ---- exact softmax per row (rows live at reg r, lanes share via 16-lane xor) ----
    float zinv[4];
    #pragma unroll
    for (int r = 0; r < 4; ++r) {
        float m = S[0][r];
        #pragma unroll
        for (int jf = 1; jf < 32; ++jf) m = fmaxf(m, S[jf][r]);
        m = fmaxf(m, __shfl_xor(m, 1, 64));
        m = fmaxf(m, __shfl_xor(m, 2, 64));
        m = fmaxf(m, __shfl_xor(m, 4, 64));
        m = fmaxf(m, __shfl_xor(m, 8, 64));
        float z = 0.f;
        #pragma unroll
        for (int jf = 0; jf < 32; ++jf) {
            float e = __expf(S[jf][r] - m);
            S[jf][r] = e;
            z += e;
        }
        z += __shfl_xor(z, 1, 64);
        z += __shfl_xor(z, 2, 64);
        z += __shfl_xor(z, 4, 64);
        z += __shfl_xor(z, 8, 64);
        zinv[r] = 1.f / z;
        if (c == 0) rowmax[b * L1 + i0 + 4 * g + r] = m;
    }

    // ---- relayout alpha (unnormalized, in [0,1]) through LDS for PV A-frags ----
    #pragma unroll
    for (int jf = 0; jf < 32; ++jf) {
        #pragma unroll
        for (int r = 0; r < 4; ++r)
            alpha_lds[w][4 * g + r][jf * 16 + c] = f2bf(S[jf][r]);
    }
    __syncthreads();

    // ---- PV: c2q = alpha @ y, B-frags k-contiguous from y_t[b][d][j] ----
    f32x4 o[16];
    #pragma unroll
    for (int nf = 0; nf < 16; ++nf) o[nf] = (f32x4){0.f, 0.f, 0.f, 0.f};
    const unsigned short* ytb = yt + ((size_t)b * DD) * L2;
    for (int kf = 0; kf < 16; ++kf) {
        bf16x8 apv = *(const bf16x8*)(&alpha_lds[w][c][kf * 32 + g * 8]);
        #pragma unroll
        for (int nf = 0; nf < 16; ++nf) {
            bf16x8 bpv = *(const bf16x8*)(ytb + (size_t)(nf * 16 + c) * L2 + kf * 32 + g * 8);
            o[nf] = __builtin_amdgcn_mfma_f32_16x16x32_bf16(apv, bpv, o[nf], 0, 0, 0);
        }
    }

    // ---- epilogue: normalize, mask, write c2q and x*c2q as FLOAT32 ----
    const float* xb2 = x + ((size_t)b * L1) * DD;
    size_t outbase = ((size_t)b * L1) * DD;
    #pragma unroll
    for (int nf = 0; nf < 16; ++nf) {
        int d = nf * 16 + c;
        #pragma unroll
        for (int r = 0; r < 4; ++r) {
            int i = i0 + 4 * g + r;
            float cv = xm[r] ? 0.f : o[nf][r] * zinv[r];
            size_t idx = outbase + (size_t)i * DD + d;
            out0[idx] = cv;
            out2[idx] = xb2[(size_t)i * DD + d] * cv;
        }
    }
}

// ---------------- beta = softmax_i(rowmax) per batch ----------------
__global__ void beta_prep(const float* __restrict__ rowmax, float* __restrict__ beta) {
    __shared__ float red[4];
    int b = blockIdx.x, tid = threadIdx.x, w = tid >> 6, lane = tid & 63;
    float v[8];
    float m = -3.0e38f;
    #pragma unroll
    for (int k = 0; k < 8; ++k) {
        v[k] = rowmax[b * L1 + k * 256 + tid];
        m = fmaxf(m, v[k]);
    }
    #pragma unroll
    for (int off = 1; off < 64; off <<= 1) m = fmaxf(m, __shfl_xor(m, off, 64));
    if (lane == 0) red[w] = m;
    __syncthreads();
    m = fmaxf(fmaxf(red[0], red[1]), fmaxf(red[2], red[3]));
    __syncthreads();
    float z = 0.f;
    #pragma unroll
    for (int k = 0; k < 8; ++k) {
        v[k] = __expf(v[k] - m);
        z += v[k];
    }
    #pragma unroll
    for (int off = 1; off < 64; off <<= 1) z += __shfl_xor(z, off, 64);
    if (lane == 0) red[w] = z;
    __syncthreads();
    z = red[0] + red[1] + red[2] + red[3];
    float zi = 1.f / z;
    #pragma unroll
    for (int k = 0; k < 8; ++k) beta[b * L1 + k * 256 + tid] = v[k] * zi;
}

// ---------------- q2c = sum_i beta_i * x_i (partials then reduce) ----------------
__global__ void q2c_partial(const float* __restrict__ x, const float* __restrict__ beta,
                            float* __restrict__ part) {
    int b = blockIdx.y, ch = blockIdx.x, d = threadIdx.x;
    const float* xb = x + ((size_t)(b * L1 + ch * 128)) * DD;
    const float* bb = beta + b * L1 + ch * 128;
    float acc = 0.f;
    #pragma unroll 8
    for (int i = 0; i < 128; ++i) acc += bb[i] * xb[(size_t)i * DD + d];
    part[((size_t)b * 16 + ch) * DD + d] = acc;
}

__global__ void q2c_final(const float* __restrict__ part, float* __restrict__ out1) {
    int b = blockIdx.x, d = threadIdx.x;
    float s = 0.f;
    #pragma unroll
    for (int ch = 0; ch < 16; ++ch) s += part[((size_t)b * 16 + ch) * DD + d];
    out1[b * DD + d] = s;
}

extern "C" void kernel_launch(void* const* d_in, const int* in_sizes, int n_in,
                              void* d_out, int out_size, void* d_ws, size_t ws_size,
                              hipStream_t stream) {
    const float* x = (const float*)d_in[0];
    const float* y = (const float*)d_in[1];
    const int* x_mask = (const int*)d_in[2];
    const int* y_mask = (const int*)d_in[3];
    const float* w_x = (const float*)d_in[4];
    const float* w_y = (const float*)d_in[5];
    const float* w_dot = (const float*)d_in[6];
    const float* bias = (const float*)d_in[7];

    char* ws = (char*)d_ws;
    unsigned short* ybf = (unsigned short*)ws;                 //  8,388,608 B
    unsigned short* yt  = (unsigned short*)(ws + 8388608);     //  8,388,608 B
    float* sy      = (float*)(ws + 16777216);                  //     65,536 B
    float* rowmax  = (float*)(ws + 16842752);                  //    262,144 B
    float* beta    = (float*)(ws + 17104896);                  //    262,144 B
    float* part    = (float*)(ws + 17367040);                  //    524,288 B  (tot ~17.9MB)

    float* out0 = (float*)d_out;                               // c2q   (B,L1,D) f32
    float* out1 = out0 + (size_t)BB * L1 * DD;                 // q2c   (B,1,D)  f32
    float* out2 = out1 + (size_t)BB * DD;                      // x*c2q (B,L1,D) f32

    prep_y<<<dim3(BB * L2 / 4), 256, 0, stream>>>(y, w_y, ybf, sy);
    transpose_y<<<dim3(32, BB), 256, 0, stream>>>(y, yt);
    attn_main<<<dim3(L1 / 64, BB), 256, 0, stream>>>(x, ybf, yt, sy, w_x, w_dot, bias,
                                                     x_mask, y_mask, rowmax, out0, out2);
    beta_prep<<<dim3(BB), 256, 0, stream>>>(rowmax, beta);
    q2c_partial<<<dim3(16, BB), 256, 0, stream>>>(x, beta, part);
    q2c_final<<<dim3(BB), 256, 0, stream>>>(part, out1);
}

// Round 5
// 211.178 us; speedup vs baseline: 1.4203x; 1.4203x over previous
//
#include <hip/hip_runtime.h>
#include <stdint.h>

#define BB 32
#define L1 2048
#define L2 512
#define DD 256
#define NEGV -1e30f

typedef __attribute__((ext_vector_type(4))) float f32x4;
typedef __attribute__((ext_vector_type(8))) short bf16x8;
typedef __attribute__((ext_vector_type(4))) unsigned short u16x4;

__device__ __forceinline__ unsigned short f2bf(float f) {
    unsigned int u = __float_as_uint(f);
    u += 0x7FFFu + ((u >> 16) & 1u);
    return (unsigned short)(u >> 16);
}

// ---------------- prep_y: y -> bf16 row-major, sy = y @ w_y ----------------
__global__ void prep_y(const float* __restrict__ y, const float* __restrict__ w_y,
                       unsigned short* __restrict__ ybf, float* __restrict__ sy) {
    int row = blockIdx.x * 4 + (threadIdx.x >> 6);   // 0 .. BB*L2-1
    int lane = threadIdx.x & 63;
    const float* yr = y + (size_t)row * DD + lane * 4;
    f32x4 v = *(const f32x4*)yr;
    f32x4 w = *(const f32x4*)(w_y + lane * 4);
    u16x4 o;
    o[0] = f2bf(v[0]); o[1] = f2bf(v[1]); o[2] = f2bf(v[2]); o[3] = f2bf(v[3]);
    *(u16x4*)(ybf + (size_t)row * DD + lane * 4) = o;
    float s = v[0]*w[0] + v[1]*w[1] + v[2]*w[2] + v[3]*w[3];
    #pragma unroll
    for (int off = 32; off; off >>= 1) s += __shfl_down(s, off, 64);
    if (lane == 0) sy[row] = s;
}

// ---------------- transpose_y: y -> bf16 [b][d][j] ----------------
__global__ void transpose_y(const float* __restrict__ y, unsigned short* __restrict__ yt) {
    __shared__ float tile[64][65];
    int b = blockIdx.y;
    int jt = blockIdx.x & 7, dt = blockIdx.x >> 3;
    int j0 = jt * 64, d0 = dt * 64;
    const float* base = y + ((size_t)b * L2) * DD;
    #pragma unroll
    for (int k = 0; k < 16; ++k) {
        int idx = k * 256 + threadIdx.x;
        int jj = idx >> 6, dd = idx & 63;
        tile[jj][dd] = base[(size_t)(j0 + jj) * DD + d0 + dd];
    }
    __syncthreads();
    unsigned short* ob = yt + ((size_t)b * DD) * L2;
    #pragma unroll
    for (int k = 0; k < 16; ++k) {
        int idx = k * 256 + threadIdx.x;
        int dd = idx >> 6, jj = idx & 63;
        ob[(size_t)(d0 + dd) * L2 + j0 + jj] = f2bf(tile[jj][dd]);
    }
}

// ---------------- main fused attention kernel ----------------
// block = 256 threads (4 waves); wave w owns rows i0 = blockIdx.x*64 + w*16 .. +15
// LDS (64 KB union):
//   scores phase: double-buffered staged y chunks, buf p = smem[p*16384 .. +16383]
//     LDS[j][u] (u=0..31 ushort) = ybf[j][ck*32 + (u ^ 8*(j&3))]   (16B-granule XOR swizzle)
//   PV phase: alpha[w][row][col] at smem[w*8192 + row*512 + (col ^ ((row&7)<<3))]
__launch_bounds__(256, 2)
__global__ void attn_main(const float* __restrict__ x,
                          const unsigned short* __restrict__ ybf,
                          const unsigned short* __restrict__ yt,
                          const float* __restrict__ sy,
                          const float* __restrict__ w_x,
                          const float* __restrict__ w_dot,
                          const float* __restrict__ bias,
                          const int* __restrict__ x_mask,
                          const int* __restrict__ y_mask,
                          float* __restrict__ rowmax,
                          float* __restrict__ out0,
                          float* __restrict__ out2) {
    __shared__ unsigned short smem[32768];   // 64 KB union (staging dbuf / alpha)
    const int tid = threadIdx.x;
    const int w = tid >> 6;
    const int lane = tid & 63;
    const int g = lane >> 4, c = lane & 15;
    const int b = blockIdx.y;
    const int i0 = blockIdx.x * 64 + w * 16;

    // ---- build xw bf16 A-fragments in registers + sx via shuffles ----
    bf16x8 afr[8];
    float sxpart = 0.f;
    const float* xrow = x + ((size_t)(b * L1 + i0 + c)) * DD;
    #pragma unroll
    for (int kb = 0; kb < 8; ++kb) {
        int koff = kb * 32 + g * 8;
        f32x4 lo = *(const f32x4*)(xrow + koff);
        f32x4 hi = *(const f32x4*)(xrow + koff + 4);
        f32x4 wdlo = *(const f32x4*)(w_dot + koff);
        f32x4 wdhi = *(const f32x4*)(w_dot + koff + 4);
        f32x4 wxlo = *(const f32x4*)(w_x + koff);
        f32x4 wxhi = *(const f32x4*)(w_x + koff + 4);
        bf16x8 a;
        #pragma unroll
        for (int e = 0; e < 4; ++e) {
            a[e]     = (short)f2bf(lo[e] * wdlo[e]);
            a[e + 4] = (short)f2bf(hi[e] * wdhi[e]);
            sxpart += lo[e] * wxlo[e] + hi[e] * wxhi[e];
        }
        afr[kb] = a;
    }
    sxpart += __shfl_xor(sxpart, 16, 64);
    sxpart += __shfl_xor(sxpart, 32, 64);
    float bias0 = bias[0];
    float sxb[4];
    int xm[4];
    #pragma unroll
    for (int r = 0; r < 4; ++r) {
        sxb[r] = __shfl(sxpart, 4 * g + r, 64) + bias0;
        xm[r] = x_mask[b * L1 + i0 + 4 * g + r];
    }

    // ---- staging setup: per-thread source with pre-swizzled global k-offset ----
    // thread t stages rows j = it*64 + (t>>2), 16 B at k = ck*32 + 8*((t&3)^((t>>2)&3))
    const unsigned short* ybase = ybf + (size_t)b * L2 * DD;
    const unsigned short* gsrc0 = ybase + (size_t)(tid >> 2) * DD + 8 * ((tid & 3) ^ ((tid >> 2) & 3));

#define STAGE(ck, buf) do {                                                              \
    const unsigned short* _gs = gsrc0 + (ck) * 32;                                       \
    unsigned short* _ld = &smem[(buf) * 16384 + tid * 8];                                \
    _Pragma("unroll")                                                                    \
    for (int _it = 0; _it < 8; ++_it) {                                                  \
        __builtin_amdgcn_global_load_lds(                                                \
            (const __attribute__((address_space(1))) unsigned int*)(_gs + (size_t)_it * 64 * DD), \
            (__attribute__((address_space(3))) unsigned int*)(_ld + _it * 2048),         \
            16, 0, 0);                                                                   \
    }                                                                                    \
} while (0)

    // ---- scores: S[16 rows][512], K-chunks of 32 staged in LDS, shared by 4 waves ----
    f32x4 S[32];
    #pragma unroll
    for (int jf = 0; jf < 32; ++jf) S[jf] = (f32x4){0.f, 0.f, 0.f, 0.f};

    STAGE(0, 0);
    __syncthreads();   // drains vmcnt (implicit) -> buf0 ready
    #pragma unroll
    for (int ck = 0; ck < 8; ++ck) {
        if (ck < 7) STAGE(ck + 1, (ck + 1) & 1);
        const unsigned short* sb = &smem[(ck & 1) * 16384];
        const int roff = 8 * (g ^ (c & 3));
        #pragma unroll
        for (int jf = 0; jf < 32; ++jf) {
            bf16x8 bfr = *(const bf16x8*)&sb[(jf * 16 + c) * 32 + roff];
            S[jf] = __builtin_amdgcn_mfma_f32_16x16x32_bf16(afr[ck], bfr, S[jf], 0, 0, 0);
        }
        __syncthreads();  // reads of buf(ck&1) done + staged buf((ck+1)&1) landed
    }

    // ---- add bias terms + masks ----
    #pragma unroll
    for (int jf = 0; jf < 32; ++jf) {
        float syv = sy[b * L2 + jf * 16 + c];
        int ym = y_mask[b * L2 + jf * 16 + c];
        #pragma unroll
        for (int r = 0; r < 4; ++r) {
            float v = S[jf][r] + sxb[r] + syv;
            if (ym) v = NEGV;
            if (xm[r]) v = NEGV;
            S[jf][r] = v;
        }
    }

    // ---- exact softmax per row ----
    float zinv[4];
    #pragma unroll
    for (int r = 0; r < 4; ++r) {
        float m = S[0][r];
        #pragma unroll
        for (int jf = 1; jf < 32; ++jf) m = fmaxf(m, S[jf][r]);
        m = fmaxf(m, __shfl_xor(m, 1, 64));
        m = fmaxf(m, __shfl_xor(m, 2, 64));
        m = fmaxf(m, __shfl_xor(m, 4, 64));
        m = fmaxf(m, __shfl_xor(m, 8, 64));
        float z = 0.f;
        #pragma unroll
        for (int jf = 0; jf < 32; ++jf) {
            float e = __expf(S[jf][r] - m);
            S[jf][r] = e;
            z += e;
        }
        z += __shfl_xor(z, 1, 64);
        z += __shfl_xor(z, 2, 64);
        z += __shfl_xor(z, 4, 64);
        z += __shfl_xor(z, 8, 64);
        zinv[r] = 1.f / z;
        if (c == 0) rowmax[b * L1 + i0 + 4 * g + r] = m;
    }

    // ---- overlay alpha into the (now dead) staging LDS, XOR-swizzled ----
    __syncthreads();   // all waves done reading staged chunks
    #pragma unroll
    for (int jf = 0; jf < 32; ++jf) {
        #pragma unroll
        for (int r = 0; r < 4; ++r) {
            int row = 4 * g + r;
            int col = jf * 16 + c;
            smem[w * 8192 + row * 512 + (col ^ ((row & 7) << 3))] = f2bf(S[jf][r]);
        }
    }
    __syncthreads();

    // ---- PV: c2q = alpha @ y, B-frags k-contiguous from y_t[b][d][j] (L2) ----
    f32x4 o[16];
    #pragma unroll
    for (int nf = 0; nf < 16; ++nf) o[nf] = (f32x4){0.f, 0.f, 0.f, 0.f};
    const unsigned short* ytb = yt + ((size_t)b * DD) * L2;
    for (int kf = 0; kf < 16; ++kf) {
        bf16x8 apv = *(const bf16x8*)&smem[w * 8192 + c * 512 + ((kf * 32 + g * 8) ^ ((c & 7) << 3))];
        #pragma unroll
        for (int nf = 0; nf < 16; ++nf) {
            bf16x8 bpv = *(const bf16x8*)(ytb + (size_t)(nf * 16 + c) * L2 + kf * 32 + g * 8);
            o[nf] = __builtin_amdgcn_mfma_f32_16x16x32_bf16(apv, bpv, o[nf], 0, 0, 0);
        }
    }

    // ---- epilogue: normalize, mask, write c2q and x*c2q as FLOAT32 ----
    const float* xb2 = x + ((size_t)b * L1) * DD;
    size_t outbase = ((size_t)b * L1) * DD;
    #pragma unroll
    for (int nf = 0; nf < 16; ++nf) {
        int d = nf * 16 + c;
        #pragma unroll
        for (int r = 0; r < 4; ++r) {
            int i = i0 + 4 * g + r;
            float cv = xm[r] ? 0.f : o[nf][r] * zinv[r];
            size_t idx = outbase + (size_t)i * DD + d;
            out0[idx] = cv;
            out2[idx] = xb2[(size_t)i * DD + d] * cv;
        }
    }
#undef STAGE
}

// ---------------- beta = softmax_i(rowmax) per batch ----------------
__global__ void beta_prep(const float* __restrict__ rowmax, float* __restrict__ beta) {
    __shared__ float red[4];
    int b = blockIdx.x, tid = threadIdx.x, w = tid >> 6, lane = tid & 63;
    float v[8];
    float m = -3.0e38f;
    #pragma unroll
    for (int k = 0; k < 8; ++k) {
        v[k] = rowmax[b * L1 + k * 256 + tid];
        m = fmaxf(m, v[k]);
    }
    #pragma unroll
    for (int off = 1; off < 64; off <<= 1) m = fmaxf(m, __shfl_xor(m, off, 64));
    if (lane == 0) red[w] = m;
    __syncthreads();
    m = fmaxf(fmaxf(red[0], red[1]), fmaxf(red[2], red[3]));
    __syncthreads();
    float z = 0.f;
    #pragma unroll
    for (int k = 0; k < 8; ++k) {
        v[k] = __expf(v[k] - m);
        z += v[k];
    }
    #pragma unroll
    for (int off = 1; off < 64; off <<= 1) z += __shfl_xor(z, off, 64);
    if (lane == 0) red[w] = z;
    __syncthreads();
    z = red[0] + red[1] + red[2] + red[3];
    float zi = 1.f / z;
    #pragma unroll
    for (int k = 0; k < 8; ++k) beta[b * L1 + k * 256 + tid] = v[k] * zi;
}

// ---------------- q2c = sum_i beta_i * x_i (partials then reduce) ----------------
__global__ void q2c_partial(const float* __restrict__ x, const float* __restrict__ beta,
                            float* __restrict__ part) {
    int b = blockIdx.y, ch = blockIdx.x, d = threadIdx.x;
    const float* xb = x + ((size_t)(b * L1 + ch * 128)) * DD;
    const float* bb = beta + b * L1 + ch * 128;
    float acc = 0.f;
    #pragma unroll 8
    for (int i = 0; i < 128; ++i) acc += bb[i] * xb[(size_t)i * DD + d];
    part[((size_t)b * 16 + ch) * DD + d] = acc;
}

__global__ void q2c_final(const float* __restrict__ part, float* __restrict__ out1) {
    int b = blockIdx.x, d = threadIdx.x;
    float s = 0.f;
    #pragma unroll
    for (int ch = 0; ch < 16; ++ch) s += part[((size_t)b * 16 + ch) * DD + d];
    out1[b * DD + d] = s;
}

extern "C" void kernel_launch(void* const* d_in, const int* in_sizes, int n_in,
                              void* d_out, int out_size, void* d_ws, size_t ws_size,
                              hipStream_t stream) {
    const float* x = (const float*)d_in[0];
    const float* y = (const float*)d_in[1];
    const int* x_mask = (const int*)d_in[2];
    const int* y_mask = (const int*)d_in[3];
    const float* w_x = (const float*)d_in[4];
    const float* w_y = (const float*)d_in[5];
    const float* w_dot = (const float*)d_in[6];
    const float* bias = (const float*)d_in[7];

    char* ws = (char*)d_ws;
    unsigned short* ybf = (unsigned short*)ws;                 //  8,388,608 B
    unsigned short* yt  = (unsigned short*)(ws + 8388608);     //  8,388,608 B
    float* sy      = (float*)(ws + 16777216);                  //     65,536 B
    float* rowmax  = (float*)(ws + 16842752);                  //    262,144 B
    float* beta    = (float*)(ws + 17104896);                  //    262,144 B
    float* part    = (float*)(ws + 17367040);                  //    524,288 B  (tot ~17.9MB)

    float* out0 = (float*)d_out;                               // c2q   (B,L1,D) f32
    float* out1 = out0 + (size_t)BB * L1 * DD;                 // q2c   (B,1,D)  f32
    float* out2 = out1 + (size_t)BB * DD;                      // x*c2q (B,L1,D) f32

    prep_y<<<dim3(BB * L2 / 4), 256, 0, stream>>>(y, w_y, ybf, sy);
    transpose_y<<<dim3(32, BB), 256, 0, stream>>>(y, yt);
    attn_main<<<dim3(L1 / 64, BB), 256, 0, stream>>>(x, ybf, yt, sy, w_x, w_dot, bias,
                                                     x_mask, y_mask, rowmax, out0, out2);
    beta_prep<<<dim3(BB), 256, 0, stream>>>(rowmax, beta);
    q2c_partial<<<dim3(16, BB), 256, 0, stream>>>(x, beta, part);
    q2c_final<<<dim3(BB), 256, 0, stream>>>(part, out1);
}

// Round 6
// 124.289 us; speedup vs baseline: 2.4133x; 1.6991x over previous
//
#include <hip/hip_runtime.h>
#include <stdint.h>

#define BB 32
#define L1 2048
#define L2 512
#define DD 256
#define NEGV -1e30f

typedef __attribute__((ext_vector_type(4))) float f32x4;
typedef __attribute__((ext_vector_type(8))) short bf16x8;
typedef __attribute__((ext_vector_type(4))) unsigned short u16x4;
typedef __attribute__((ext_vector_type(8))) unsigned short u16x8;

__device__ __forceinline__ unsigned short f2bf(float f) {
    unsigned int u = __float_as_uint(f);
    u += 0x7FFFu + ((u >> 16) & 1u);
    return (unsigned short)(u >> 16);
}

// ---- prep: fused y -> ybf (bf16 [b][j][d]), yt (bf16 [b][d][j]), sy = y@w_y ----
__global__ void prep(const float* __restrict__ y, const float* __restrict__ w_y,
                     unsigned short* __restrict__ ybf, unsigned short* __restrict__ yt,
                     float* __restrict__ sy) {
    __shared__ float tile[64][264];   // pad 256->264: aligned 16B rows, write-side conflict-free
    const int tid = threadIdx.x;
    const int lane = tid & 63;
    const int sub = tid >> 6;
    const int b = blockIdx.y;
    const int j0 = blockIdx.x * 64;
    const float* yb = y + ((size_t)b * L2 + j0) * DD;
    f32x4 wv = *(const f32x4*)(w_y + lane * 4);
    #pragma unroll
    for (int p = 0; p < 16; ++p) {
        int row = p * 4 + sub;
        f32x4 v = *(const f32x4*)(yb + (size_t)row * DD + lane * 4);
        *(f32x4*)&tile[row][lane * 4] = v;
        u16x4 o;
        o[0] = f2bf(v[0]); o[1] = f2bf(v[1]); o[2] = f2bf(v[2]); o[3] = f2bf(v[3]);
        *(u16x4*)(ybf + ((size_t)b * L2 + j0 + row) * DD + lane * 4) = o;
        float s = v[0]*wv[0] + v[1]*wv[1] + v[2]*wv[2] + v[3]*wv[3];
        #pragma unroll
        for (int off = 32; off; off >>= 1) s += __shfl_xor(s, off, 64);
        if (lane == 0) sy[b * L2 + j0 + row] = s;
    }
    __syncthreads();
    #pragma unroll
    for (int p = 0; p < 8; ++p) {
        int d = p * 32 + (tid >> 3);
        int jo = (tid & 7) * 8;
        u16x8 pk;
        #pragma unroll
        for (int jj = 0; jj < 8; ++jj) pk[jj] = f2bf(tile[jo + jj][d]);
        *(u16x8*)(yt + ((size_t)b * DD + d) * L2 + j0 + jo) = pk;
    }
}

// ---- main fused kernel: col-split scores + cross-wave softmax + d-split PV ----
// block = 256 thr (4 waves), owns 64 rows of one batch.
// LDS union `big` (64 KB): phase A/B = xw[64][256] bf16 swizzled; phase D/E = alpha[64][512] bf16 swizzled.
__launch_bounds__(256, 2)
__global__ void attn_main(const float* __restrict__ x,
                          const unsigned short* __restrict__ ybf,
                          const unsigned short* __restrict__ yt,
                          const float* __restrict__ sy,
                          const float* __restrict__ w_x,
                          const float* __restrict__ w_dot,
                          const float* __restrict__ bias,
                          const int* __restrict__ x_mask,
                          const int* __restrict__ y_mask,
                          float* __restrict__ out0,
                          float* __restrict__ out2,
                          float* __restrict__ part,
                          float* __restrict__ MbA,
                          float* __restrict__ SeA) {
    __shared__ __align__(16) unsigned short big[32768];
    __shared__ float sxs[64];
    __shared__ int   xms[64];
    __shared__ float pmax[4][64];
    __shared__ float pz[4][64];

    const int tid = threadIdx.x;
    const int w = tid >> 6;
    const int lane = tid & 63;
    const int g = lane >> 4, c = lane & 15;

    // XCD-aware bijective decode: batch pinned to one XCD (8 XCDs round-robin assumed;
    // wrong assumption only costs L2 locality, never correctness)
    const int wg = blockIdx.x;
    const int slot = wg >> 3;
    const int b = (wg & 7) * 4 + (slot >> 5);
    const int rowblk = slot & 31;
    const int i0 = rowblk * 64;

    // ---- Phase A: build xw bf16 -> LDS (swizzled), sx, x-mask ----
    const int arow = w * 16 + c;
    const float* xrow = x + ((size_t)(b * L1 + i0 + arow)) * DD;
    float sxpart = 0.f;
    #pragma unroll
    for (int kb = 0; kb < 8; ++kb) {
        int koff = kb * 32 + g * 8;
        f32x4 lo = *(const f32x4*)(xrow + koff);
        f32x4 hi = *(const f32x4*)(xrow + koff + 4);
        f32x4 wdlo = *(const f32x4*)(w_dot + koff);
        f32x4 wdhi = *(const f32x4*)(w_dot + koff + 4);
        f32x4 wxlo = *(const f32x4*)(w_x + koff);
        f32x4 wxhi = *(const f32x4*)(w_x + koff + 4);
        u16x8 a;
        #pragma unroll
        for (int e = 0; e < 4; ++e) {
            a[e]     = f2bf(lo[e] * wdlo[e]);
            a[e + 4] = f2bf(hi[e] * wdhi[e]);
            sxpart += lo[e] * wxlo[e] + hi[e] * wxhi[e];
        }
        int u = (kb * 4 + g) ^ (c & 7);
        *(u16x8*)((char*)big + arow * 512 + u * 16) = a;
    }
    sxpart += __shfl_xor(sxpart, 16, 64);
    sxpart += __shfl_xor(sxpart, 32, 64);
    if (g == 0) {
        sxs[arow] = sxpart + bias[0];
        xms[arow] = x_mask[b * L1 + i0 + arow];
    }
    __syncthreads();                                   // B1: xw/sxs/xms ready

    // ---- Phase B: scores, wave w owns cols [w*128, w*128+128) for all 64 rows ----
    f32x4 S[4][8];
    #pragma unroll
    for (int mt = 0; mt < 4; ++mt)
        #pragma unroll
        for (int nt = 0; nt < 8; ++nt) S[mt][nt] = (f32x4){0.f, 0.f, 0.f, 0.f};

    const unsigned short* ybase = ybf + (size_t)b * L2 * DD;
    const int col0 = w * 128;
    #pragma unroll 2
    for (int ck = 0; ck < 8; ++ck) {
        bf16x8 bfr[8];
        #pragma unroll
        for (int nt = 0; nt < 8; ++nt)
            bfr[nt] = *(const bf16x8*)(ybase + (size_t)(col0 + nt * 16 + c) * DD + ck * 32 + g * 8);
        bf16x8 afr[4];
        #pragma unroll
        for (int mt = 0; mt < 4; ++mt) {
            int u = (ck * 4 + g) ^ (c & 7);
            afr[mt] = *(const bf16x8*)((char*)big + (mt * 16 + c) * 512 + u * 16);
        }
        #pragma unroll
        for (int mt = 0; mt < 4; ++mt)
            #pragma unroll
            for (int nt = 0; nt < 8; ++nt)
                S[mt][nt] = __builtin_amdgcn_mfma_f32_16x16x32_bf16(afr[mt], bfr[nt], S[mt][nt], 0, 0, 0);
    }

    float syv[8]; int ymv[8];
    #pragma unroll
    for (int nt = 0; nt < 8; ++nt) {
        syv[nt] = sy[b * L2 + col0 + nt * 16 + c];
        ymv[nt] = y_mask[b * L2 + col0 + nt * 16 + c];
    }
    float sxr[4][4]; int xmr[4][4];
    #pragma unroll
    for (int mt = 0; mt < 4; ++mt)
        #pragma unroll
        for (int r = 0; r < 4; ++r) {
            sxr[mt][r] = sxs[mt * 16 + 4 * g + r];
            xmr[mt][r] = xms[mt * 16 + 4 * g + r];
        }
    #pragma unroll
    for (int mt = 0; mt < 4; ++mt)
        #pragma unroll
        for (int nt = 0; nt < 8; ++nt)
            #pragma unroll
            for (int r = 0; r < 4; ++r) {
                float v = S[mt][nt][r] + sxr[mt][r] + syv[nt];
                if (ymv[nt]) v = NEGV;
                if (xmr[mt][r]) v = NEGV;
                S[mt][nt][r] = v;
            }

    // ---- Phase C: cross-wave exact softmax (max, then exp+sum) ----
    float mrow[4][4];
    #pragma unroll
    for (int mt = 0; mt < 4; ++mt)
        #pragma unroll
        for (int r = 0; r < 4; ++r) {
            float pm = S[mt][0][r];
            #pragma unroll
            for (int nt = 1; nt < 8; ++nt) pm = fmaxf(pm, S[mt][nt][r]);
            pm = fmaxf(pm, __shfl_xor(pm, 1, 64));
            pm = fmaxf(pm, __shfl_xor(pm, 2, 64));
            pm = fmaxf(pm, __shfl_xor(pm, 4, 64));
            pm = fmaxf(pm, __shfl_xor(pm, 8, 64));
            if (c == 0) pmax[w][mt * 16 + 4 * g + r] = pm;
        }
    __syncthreads();                                   // B2
    #pragma unroll
    for (int mt = 0; mt < 4; ++mt)
        #pragma unroll
        for (int r = 0; r < 4; ++r) {
            int row = mt * 16 + 4 * g + r;
            mrow[mt][r] = fmaxf(fmaxf(pmax[0][row], pmax[1][row]),
                                fmaxf(pmax[2][row], pmax[3][row]));
        }
    #pragma unroll
    for (int mt = 0; mt < 4; ++mt)
        #pragma unroll
        for (int r = 0; r < 4; ++r) {
            float zp = 0.f;
            #pragma unroll
            for (int nt = 0; nt < 8; ++nt) {
                float e = __expf(S[mt][nt][r] - mrow[mt][r]);
                S[mt][nt][r] = e;
                zp += e;
            }
            zp += __shfl_xor(zp, 1, 64);
            zp += __shfl_xor(zp, 2, 64);
            zp += __shfl_xor(zp, 4, 64);
            zp += __shfl_xor(zp, 8, 64);
            if (c == 0) pz[w][mt * 16 + 4 * g + r] = zp;
        }
    __syncthreads();                                   // B3 (also: all xw reads done)
    float zinv[4][4];
    #pragma unroll
    for (int mt = 0; mt < 4; ++mt)
        #pragma unroll
        for (int r = 0; r < 4; ++r) {
            int row = mt * 16 + 4 * g + r;
            zinv[mt][r] = 1.f / (pz[0][row] + pz[1][row] + pz[2][row] + pz[3][row]);
        }

    // beta ingredients: block max Mb, e_i = exp(m_i - Mb), Se = sum e_i
    float Mb;
    {
        float t = mrow[0][0];
        #pragma unroll
        for (int mt = 0; mt < 4; ++mt)
            #pragma unroll
            for (int r = 0; r < 4; ++r) t = fmaxf(t, mrow[mt][r]);
        t = fmaxf(t, __shfl_xor(t, 16, 64));
        t = fmaxf(t, __shfl_xor(t, 32, 64));
        Mb = t;
    }
    float ev[4][4];
    float Se = 0.f;
    #pragma unroll
    for (int mt = 0; mt < 4; ++mt)
        #pragma unroll
        for (int r = 0; r < 4; ++r) {
            ev[mt][r] = __expf(mrow[mt][r] - Mb);
            Se += ev[mt][r];
        }
    Se += __shfl_xor(Se, 16, 64);
    Se += __shfl_xor(Se, 32, 64);
    if (tid == 0) {
        MbA[b * 32 + rowblk] = Mb;
        SeA[b * 32 + rowblk] = Se;
    }

    // ---- Phase D: alpha -> LDS (overlays xw), granule-swizzled ----
    #pragma unroll
    for (int mt = 0; mt < 4; ++mt)
        #pragma unroll
        for (int nt = 0; nt < 8; ++nt)
            #pragma unroll
            for (int r = 0; r < 4; ++r) {
                int row = mt * 16 + 4 * g + r;
                int col = col0 + nt * 16 + c;
                *(unsigned short*)((char*)big + row * 1024 +
                                   (((col >> 3) ^ (row & 7)) * 16) + (col & 7) * 2)
                    = f2bf(S[mt][nt][r]);
            }
    __syncthreads();                                   // B4: alpha ready

    // ---- Phase E: PV, wave w owns d in [w*64, w*64+64) for all 64 rows ----
    f32x4 o[4][4];
    #pragma unroll
    for (int mt = 0; mt < 4; ++mt)
        #pragma unroll
        for (int nt = 0; nt < 4; ++nt) o[mt][nt] = (f32x4){0.f, 0.f, 0.f, 0.f};
    const unsigned short* ytb = yt + (size_t)b * DD * L2;
    const int d0 = w * 64;
    #pragma unroll 4
    for (int kf = 0; kf < 16; ++kf) {
        bf16x8 bv[4];
        #pragma unroll
        for (int nt = 0; nt < 4; ++nt)
            bv[nt] = *(const bf16x8*)(ytb + (size_t)(d0 + nt * 16 + c) * L2 + kf * 32 + g * 8);
        bf16x8 av[4];
        #pragma unroll
        for (int mt = 0; mt < 4; ++mt) {
            int u = (kf * 4 + g) ^ (c & 7);
            av[mt] = *(const bf16x8*)((char*)big + (mt * 16 + c) * 1024 + u * 16);
        }
        #pragma unroll
        for (int mt = 0; mt < 4; ++mt)
            #pragma unroll
            for (int nt = 0; nt < 4; ++nt)
                o[mt][nt] = __builtin_amdgcn_mfma_f32_16x16x32_bf16(av[mt], bv[nt], o[mt][nt], 0, 0, 0);
    }

    // ---- Phase F: epilogue: normalize, mask, write out0/out2, q2c partial ----
    const float* xb2 = x + ((size_t)b * L1 + i0) * DD;
    const size_t outb = ((size_t)b * L1 + i0) * DD;
    float eq[4] = {0.f, 0.f, 0.f, 0.f};
    #pragma unroll
    for (int mt = 0; mt < 4; ++mt)
        #pragma unroll
        for (int r = 0; r < 4; ++r) {
            int row = mt * 16 + 4 * g + r;
            float zi = zinv[mt][r];
            float ee = ev[mt][r];
            int xmv = xmr[mt][r];
            #pragma unroll
            for (int nt = 0; nt < 4; ++nt) {
                int d = d0 + nt * 16 + c;
                float xv = xb2[(size_t)row * DD + d];
                float cv = xmv ? 0.f : o[mt][nt][r] * zi;
                out0[outb + (size_t)row * DD + d] = cv;
                out2[outb + (size_t)row * DD + d] = xv * cv;
                eq[nt] += ee * xv;
            }
        }
    #pragma unroll
    for (int nt = 0; nt < 4; ++nt) {
        float v = eq[nt];
        v += __shfl_xor(v, 16, 64);
        v += __shfl_xor(v, 32, 64);
        if (g == 0) part[((size_t)(b * 32 + rowblk)) * DD + d0 + nt * 16 + c] = v;
    }
}

// ---- combine: beta softmax across blocks, q2c = weighted partial sums ----
__global__ void q2c_combine(const float* __restrict__ part, const float* __restrict__ MbA,
                            const float* __restrict__ SeA, float* __restrict__ out1) {
    int b = blockIdx.x, d = threadIdx.x;
    float M = -3.0e38f;
    #pragma unroll
    for (int k = 0; k < 32; ++k) M = fmaxf(M, MbA[b * 32 + k]);
    float Z = 0.f, s = 0.f;
    #pragma unroll
    for (int k = 0; k < 32; ++k) {
        float wk = __expf(MbA[b * 32 + k] - M);
        Z += SeA[b * 32 + k] * wk;
        s += part[((size_t)(b * 32 + k)) * DD + d] * wk;
    }
    out1[b * DD + d] = s / Z;
}

extern "C" void kernel_launch(void* const* d_in, const int* in_sizes, int n_in,
                              void* d_out, int out_size, void* d_ws, size_t ws_size,
                              hipStream_t stream) {
    const float* x = (const float*)d_in[0];
    const float* y = (const float*)d_in[1];
    const int* x_mask = (const int*)d_in[2];
    const int* y_mask = (const int*)d_in[3];
    const float* w_x = (const float*)d_in[4];
    const float* w_y = (const float*)d_in[5];
    const float* w_dot = (const float*)d_in[6];
    const float* bias = (const float*)d_in[7];

    char* ws = (char*)d_ws;
    unsigned short* ybf = (unsigned short*)ws;              //  8,388,608 B
    unsigned short* yt  = (unsigned short*)(ws + 8388608);  //  8,388,608 B
    float* sy   = (float*)(ws + 16777216);                  //     65,536 B
    float* part = (float*)(ws + 16842752);                  //  1,048,576 B
    float* MbA  = (float*)(ws + 17891328);                  //      4,096 B
    float* SeA  = (float*)(ws + 17895424);                  //      4,096 B

    float* out0 = (float*)d_out;                            // c2q   (B,L1,D) f32
    float* out1 = out0 + (size_t)BB * L1 * DD;              // q2c   (B,1,D)  f32
    float* out2 = out1 + (size_t)BB * DD;                   // x*c2q (B,L1,D) f32

    prep<<<dim3(L2 / 64, BB), 256, 0, stream>>>(y, w_y, ybf, yt, sy);
    attn_main<<<dim3(BB * L1 / 64), 256, 0, stream>>>(x, ybf, yt, sy, w_x, w_dot, bias,
                                                      x_mask, y_mask, out0, out2,
                                                      part, MbA, SeA);
    q2c_combine<<<dim3(BB), 256, 0, stream>>>(part, MbA, SeA, out1);
}